// Round 14
// baseline (2120.879 us; speedup 1.0000x reference)
//
#include <hip/hip_runtime.h>

#define MM 200000      // messages
#define AA 100000      // atoms
#define KA 6
#define KB 5
#define NATOM 120
#define NBOND 4
#define NC (NATOM*NBOND)   // 480 combos
#define HH 256
#define HU_B 768           // bytes per state row: [h bf16 512B | uh fp8 256B]
#define NS_B (MM*KB)       // 1,000,000 bgraph slots
#define NS_A (AA*KA)       // 600,000 agraph slots

typedef unsigned char  u8;
typedef unsigned short ushort_t;
typedef __attribute__((ext_vector_type(8))) short bf16x8;
typedef __attribute__((ext_vector_type(8))) unsigned short u16x8;
typedef __attribute__((ext_vector_type(4))) float f32x4;
typedef __attribute__((ext_vector_type(2))) float f32x2;
typedef __attribute__((ext_vector_type(4))) unsigned int u32x4;
typedef __attribute__((ext_vector_type(2))) unsigned int u32x2;

#define SBAR() __builtin_amdgcn_sched_barrier(0)

// canonical bf16 weight arena offsets (ushort elements)
#define OFF_Ea   0
#define OFF_Eb   30720
#define OFF_Wz   31744
#define OFF_Wzb  228352
#define OFF_Wr   228608
#define OFF_Ur   359680
#define OFF_Urb  425216
#define OFF_Wh   425472
#define OFF_Whb  622080
#define OFF_O1   622336
#define OFF_O1b  753408
#define OFF_O2   753664
#define OFF_O2b  819200
#define W_TOTAL  819456

// ---------------- static device state ----------------
__device__ u8       g_exp0[(size_t)NS_B*HU_B];  // expanded slot-ordered state (ping)
__device__ u8       g_exp1[(size_t)NS_B*HU_B];  // (pong)
__device__ u8       g_texp[(size_t)NS_A*512];   // expanded h for tail (512B/slot)
__device__ u8       g_tab[481*HU_B];            // h1|uh1 per combo (row 480 = zeros)
__device__ ushort_t g_trb[NC*HH];     // bf16: x@Wr^T + Ur_b per combo
__device__ float    g_tz[NC*HH];      // x-part of z preact + Wz_b
__device__ float    g_th[NC*HH];      // x-part of h preact + Wh_b
__device__ float    g_to1[NATOM*HH];  // hnode-part of O1 preact + O1_b
__device__ int      g_cidx[MM];
__device__ ushort_t c_w[W_TOTAL];     // canonical bf16 weights
__device__ int      g_isf32;          // 1 if float inputs are f32
// inverse-graph CSR (rebuilt every call; deterministic output)
__device__ int      g_boff[MM], g_bcnt[MM], g_bsl[NS_B];
__device__ int      g_aoff[MM], g_acnt[MM], g_asl[NS_A];
__device__ int      g_cur[2];

// ---------------- helpers ----------------
__device__ inline float bf2f(ushort_t u){ return __uint_as_float(((unsigned)u)<<16); }
__device__ inline ushort_t f2bf(float f){
  unsigned u = __float_as_uint(f);
  unsigned r = (u + 0x7FFFu + ((u>>16)&1u)) >> 16;
  return (ushort_t)r;
}
__device__ inline float sigm(float x){
  return __builtin_amdgcn_rcpf(1.0f + __expf(-x));
}
__device__ inline float tanh_f(float x){
  float ax = fabsf(x);
  float e = __expf(-2.0f*ax);
  float t = (1.0f - e) * __builtin_amdgcn_rcpf(1.0f + e);
  return copysignf(t, x);
}
// LDS swizzle: ushort-index within a [rows][256] bf16 tile (XOR bits 3..5 by row&7)
__device__ inline int sidx(int row, int col){ return row*256 + (col ^ ((row&7)<<3)); }

__device__ inline bf16x8 ldsA(const ushort_t* tile, int m0, int lane, int k0){
  int row = m0 + (lane & 15);
  int col = k0 + 8*(lane>>4);
  return *(const bf16x8*)(tile + sidx(row, col));
}
__device__ inline bf16x8 ldgB(const ushort_t* W, int ldw, int koff, int n0, int lane, int k0){
  int n = n0 + (lane & 15);
  int k = koff + k0 + 8*(lane>>4);
  return *(const bf16x8*)(W + n*ldw + k);
}
__device__ inline f32x4 mfma16(bf16x8 a, bf16x8 b, f32x4 c){
  return __builtin_amdgcn_mfma_f32_16x16x32_bf16(a, b, c, 0, 0, 0);
}

// ---------------- K-detect: is the float data f32 or bf16? ------------------
__global__ __launch_bounds__(256) void k_detect(const ushort_t* Ea_raw){
  __shared__ int sbad;
  if (threadIdx.x == 0) sbad = 0;
  __syncthreads();
  float v = bf2f(Ea_raw[2*threadIdx.x]);
  float av = fabsf(v);
  int bad = (av > 1e4f) || (av != 0.0f && av < 1e-30f);
  atomicAdd(&sbad, bad);
  __syncthreads();
  if (threadIdx.x == 0) g_isf32 = (sbad > 64) ? 1 : 0;
}

// ---------------- K-convert: build canonical bf16 arena ---------------------
__global__ __launch_bounds__(256) void k_convert(
    const void* Ea, const void* Eb, const void* Wz, const void* Wzb,
    const void* Wr, const void* Ur, const void* Urb, const void* Wh,
    const void* Whb, const void* O1, const void* O1b, const void* O2,
    const void* O2b)
{
  int idx = blockIdx.x*256 + threadIdx.x;
  if (idx >= W_TOTAL) return;
  const void* src; int j;
  if      (idx < OFF_Eb)  { src = Ea;  j = idx - OFF_Ea; }
  else if (idx < OFF_Wz)  { src = Eb;  j = idx - OFF_Eb; }
  else if (idx < OFF_Wzb) { src = Wz;  j = idx - OFF_Wz; }
  else if (idx < OFF_Wr)  { src = Wzb; j = idx - OFF_Wzb; }
  else if (idx < OFF_Ur)  { src = Wr;  j = idx - OFF_Wr; }
  else if (idx < OFF_Urb) { src = Ur;  j = idx - OFF_Ur; }
  else if (idx < OFF_Wh)  { src = Urb; j = idx - OFF_Urb; }
  else if (idx < OFF_Whb) { src = Wh;  j = idx - OFF_Wh; }
  else if (idx < OFF_O1)  { src = Whb; j = idx - OFF_Whb; }
  else if (idx < OFF_O1b) { src = O1;  j = idx - OFF_O1; }
  else if (idx < OFF_O2)  { src = O1b; j = idx - OFF_O1b; }
  else if (idx < OFF_O2b) { src = O2;  j = idx - OFF_O2; }
  else                    { src = O2b; j = idx - OFF_O2b; }
  ushort_t v;
  if (g_isf32) v = f2bf(((const float*)src)[j]);
  else         v = ((const ushort_t*)src)[j];
  c_w[idx] = v;
}

// ---------------- K0: build tables -----------------------------------------
__global__ __launch_bounds__(256) void k_tables()
{
  const ushort_t* Ea  = c_w + OFF_Ea;
  const ushort_t* Eb  = c_w + OFF_Eb;
  int b = blockIdx.x, o = threadIdx.x;
  if (b < 3*NC) {
    int t = b / NC, c = b % NC, a = c >> 2, bd = c & 3;
    const ushort_t* W; const ushort_t* bias; int ldw;
    if (t == 0)      { W = c_w + OFF_Wr; bias = c_w + OFF_Urb; ldw = 512; }
    else if (t == 1) { W = c_w + OFF_Wz; bias = c_w + OFF_Wzb; ldw = 768; }
    else             { W = c_w + OFF_Wh; bias = c_w + OFF_Whb; ldw = 768; }
    float acc = bf2f(bias[o]);
    const ushort_t* wrow = W + o*ldw;
    for (int d = 0; d < 256; d++) acc += bf2f(Ea[a*256+d]) * bf2f(wrow[d]);
    for (int d = 0; d < 256; d++) acc += bf2f(Eb[bd*256+d]) * bf2f(wrow[256+d]);
    if (t == 0)      g_trb[c*256 + o] = f2bf(acc);
    else if (t == 1) g_tz[c*256 + o] = acc;
    else             g_th[c*256 + o] = acc;
  } else {
    int a = b - 3*NC;
    float acc = bf2f(c_w[OFF_O1b + o]);
    const ushort_t* wrow = c_w + OFF_O1 + o*512;
    for (int d = 0; d < 256; d++) acc += bf2f(Ea[a*256+d]) * bf2f(wrow[d]);
    g_to1[a*256 + o] = acc;
  }
}

// ---------------- K1: combo index per message ------------------------------
__global__ __launch_bounds__(256) void k_cidx(const int* fnode, const int* fsrc, const int* fbond){
  int m = blockIdx.x*256 + threadIdx.x;
  if (m >= MM) return;
  g_cidx[m] = fnode[fsrc[m]]*4 + fbond[m];
}

// ---------------- inverse-CSR build ----------------------------------------
__global__ __launch_bounds__(256) void k_zero(){
  int m = blockIdx.x*256 + threadIdx.x;
  if (m < MM){ g_bcnt[m] = 0; g_acnt[m] = 0; }
  if (m == 0){ g_cur[0] = 0; g_cur[1] = 0; }
}
__global__ __launch_bounds__(256) void k_count(const int* bgraph, const int* agraph){
  int s = blockIdx.x*256 + threadIdx.x;
  if (s < NS_B) atomicAdd(&g_bcnt[bgraph[s]], 1);
  else if (s < NS_B + NS_A) atomicAdd(&g_acnt[agraph[s - NS_B]], 1);
}
__global__ __launch_bounds__(256) void k_alloc(){
  int j = blockIdx.x*256 + threadIdx.x;
  int lane = threadIdx.x & 63;
  // b-side
  {
    int c = (j < MM) ? g_bcnt[j] : 0;
    int incl = c;
    #pragma unroll
    for (int d = 1; d < 64; d <<= 1){
      int n = __shfl_up(incl, d);
      if (lane >= d) incl += n;
    }
    int wtot = __shfl(incl, 63);
    int wbase = 0;
    if (lane == 63) wbase = atomicAdd(&g_cur[0], wtot);
    wbase = __shfl(wbase, 63);
    if (j < MM){ g_boff[j] = wbase + incl - c; g_bcnt[j] = 0; }
  }
  // a-side
  {
    int c = (j < MM) ? g_acnt[j] : 0;
    int incl = c;
    #pragma unroll
    for (int d = 1; d < 64; d <<= 1){
      int n = __shfl_up(incl, d);
      if (lane >= d) incl += n;
    }
    int wtot = __shfl(incl, 63);
    int wbase = 0;
    if (lane == 63) wbase = atomicAdd(&g_cur[1], wtot);
    wbase = __shfl(wbase, 63);
    if (j < MM){ g_aoff[j] = wbase + incl - c; g_acnt[j] = 0; }
  }
}
__global__ __launch_bounds__(256) void k_fill(const int* bgraph, const int* agraph){
  int s = blockIdx.x*256 + threadIdx.x;
  if (s < NS_B){
    int j = bgraph[s];
    int p = atomicAdd(&g_bcnt[j], 1);
    g_bsl[g_boff[j] + p] = s;
  } else if (s < NS_B + NS_A){
    int s2 = s - NS_B;
    int j = agraph[s2];
    int p = atomicAdd(&g_acnt[j], 1);
    g_asl[g_aoff[j] + p] = s2;
  }
}

// ---------------- K-tab0: 481-row h1|uh1 combo table ------------------------
__global__ __launch_bounds__(256) void k_tab0(){
  __shared__ ushort_t sh[256];
  int b = blockIdx.x, o = threadIdx.x;
  u8* row = g_tab + (size_t)b*HU_B;
  if (b == 480){
    ((ushort_t*)row)[o] = 0;
    row[512 + o] = 0;   // fp8 zero
    return;
  }
  float h = sigm(g_tz[b*256+o]) * tanh_f(g_th[b*256+o]);
  ushort_t hb = f2bf(h);
  ((ushort_t*)row)[o] = hb;
  sh[o] = hb;
  __syncthreads();
  const ushort_t* ur = c_w + OFF_Ur + o*256;
  float acc = 0.f;
  for (int d = 0; d < 256; d++) acc += bf2f(sh[d]) * bf2f(ur[d]);
  int pk = __builtin_amdgcn_cvt_pk_fp8_f32(acc, acc, 0, 0);
  row[512 + o] = (u8)(pk & 0xFF);
}

// ---------------- K-fused: gather + GRU + Uh + SCATTER (push) --------------
// 32-row tiles, 256 threads. tbl=1: read combo table (translated slots).
// tbl=0: STREAM-read expanded slots (contiguous per message).
// Output: scatter h|uh rows to next expanded buffer via inverse-CSR
// (last=1: scatter h-only to g_texp via agraph inverse-CSR).
__global__ __launch_bounds__(256,4) void k_fused(const int* __restrict__ bgraph, int rd, int tbl, int last){
  __shared__ __align__(16) ushort_t sA[32*256];  // sum_h -> uh fp8 staging (bytes)
  __shared__ __align__(16) ushort_t sB[32*256];  // sum_gated -> h_new
  __shared__ int sC[32];
  __shared__ int sJ[32*KB];
  const u8* __restrict__ src = rd ? g_exp1 : g_exp0;
  u8* dst = rd ? g_exp0 : g_exp1;
  const ushort_t* Wz = c_w + OFF_Wz;
  const ushort_t* Wh = c_w + OFF_Wh;
  const ushort_t* Ur = c_w + OFF_Ur;
  int base = blockIdx.x*32, t = threadIdx.x;
  int w = t>>6, lane = t&63;
  int sub = lane & 31, half = lane >> 5;

  // ---- header ----
  if (t < 32)  sC[t] = g_cidx[base + t];
  if (tbl && t < 32*KB){
    int j = bgraph[base*KB + t];
    sJ[t] = (j == 0) ? 480 : g_cidx[j];
  }
  __syncthreads();

  // ---- gather: 8 rows/wave as 4 pairs, 2-deep pipeline ----
  auto issue = [&](int p, bf16x8 (&hv)[KB], u32x2 (&uv)[KB], bf16x8& trv){
    int row = w*8 + 2*p + half;
    trv = *(const bf16x8*)(g_trb + sC[row]*256 + sub*8);
    if (tbl){
      #pragma unroll
      for (int k = 0; k < KB; k++){
        const u8* rp = g_tab + (size_t)sJ[row*KB + k]*HU_B;
        hv[k] = *(const bf16x8*)(rp + sub*16);
        uv[k] = *(const u32x2*)(rp + 512 + sub*8);
      }
    } else {
      const u8* rp0 = src + ((size_t)(base+row)*KB)*HU_B;
      #pragma unroll
      for (int k = 0; k < KB; k++){
        hv[k] = *(const bf16x8*)(rp0 + (size_t)k*HU_B + sub*16);
        uv[k] = *(const u32x2*)(rp0 + (size_t)k*HU_B + 512 + sub*8);
      }
    }
  };
  auto process = [&](int p, bf16x8 (&hv)[KB], u32x2 (&uv)[KB], bf16x8& trv){
    int row = w*8 + 2*p + half;
    float tre[8];
    #pragma unroll
    for (int e = 0; e < 8; e++) tre[e] = bf2f((ushort_t)trv[e]);
    float sh[8] = {0,0,0,0,0,0,0,0};
    float sg[8] = {0,0,0,0,0,0,0,0};
    #pragma unroll
    for (int k = 0; k < KB; k++){
      f32x2 d0 = __builtin_amdgcn_cvt_pk_f32_fp8(uv[k].x, 0);
      f32x2 d1 = __builtin_amdgcn_cvt_pk_f32_fp8(uv[k].x, 1);
      f32x2 d2 = __builtin_amdgcn_cvt_pk_f32_fp8(uv[k].y, 0);
      f32x2 d3 = __builtin_amdgcn_cvt_pk_f32_fp8(uv[k].y, 1);
      float uvf[8] = {d0.x, d0.y, d1.x, d1.y, d2.x, d2.y, d3.x, d3.y};
      #pragma unroll
      for (int e = 0; e < 8; e++){
        float h = bf2f((ushort_t)hv[k][e]);
        float r = sigm(tre[e] + uvf[e]);
        sh[e] += h;
        sg[e] += r*h;
      }
    }
    u16x8 ph, pg;
    #pragma unroll
    for (int e = 0; e < 8; e++){ ph[e] = f2bf(sh[e]); pg[e] = f2bf(sg[e]); }
    *(u16x8*)(sA + sidx(row, sub*8)) = ph;
    *(u16x8*)(sB + sidx(row, sub*8)) = pg;
  };
  {
    bf16x8 h0[KB], h1[KB];
    u32x2 u0[KB], u1[KB];
    bf16x8 t0v, t1v;
    issue(0, h0, u0, t0v);
    issue(1, h1, u1, t1v);
    SBAR();
    process(0, h0, u0, t0v);
    issue(2, h0, u0, t0v);
    SBAR();
    process(1, h1, u1, t1v);
    issue(3, h1, u1, t1v);
    SBAR();
    process(2, h0, u0, t0v);
    process(3, h1, u1, t1v);
  }
  __syncthreads();

  // ---- GEMM phase: z (sA x Wz) and pre_h (sB x Wh), M=32 ----
  int n0w = w*64, ln = lane&15, hi = lane>>4;
  f32x4 accz[2][4], acch[2][4];
  #pragma unroll
  for (int i=0;i<2;i++)
    #pragma unroll
    for (int j=0;j<4;j++){ accz[i][j]=(f32x4){0,0,0,0}; acch[i][j]=(f32x4){0,0,0,0}; }
  for (int kt = 0; kt < 8; kt++){
    int k0 = kt*32;
    bf16x8 aF[2], bF[4];
    aF[0] = ldsA(sA, 0, lane, k0);
    aF[1] = ldsA(sA, 16, lane, k0);
    #pragma unroll
    for (int i=0;i<4;i++) bF[i] = ldgB(Wz, 768, 512, n0w + i*16, lane, k0);
    #pragma unroll
    for (int mi=0;mi<2;mi++)
      #pragma unroll
      for (int ni=0;ni<4;ni++) accz[mi][ni] = mfma16(aF[mi], bF[ni], accz[mi][ni]);
  }
  for (int kt = 0; kt < 8; kt++){
    int k0 = kt*32;
    bf16x8 aF[2], bF[4];
    aF[0] = ldsA(sB, 0, lane, k0);
    aF[1] = ldsA(sB, 16, lane, k0);
    #pragma unroll
    for (int i=0;i<4;i++) bF[i] = ldgB(Wh, 768, 512, n0w + i*16, lane, k0);
    #pragma unroll
    for (int mi=0;mi<2;mi++)
      #pragma unroll
      for (int ni=0;ni<4;ni++) acch[mi][ni] = mfma16(aF[mi], bF[ni], acch[mi][ni]);
  }
  __syncthreads();   // all waves done reading sA/sB

  // ---- epilogue: GRU update into sB ----
  #pragma unroll
  for (int mi=0;mi<2;mi++)
    #pragma unroll
    for (int ni=0;ni<4;ni++){
      int col = n0w + ni*16 + ln;
      #pragma unroll
      for (int r=0;r<4;r++){
        int rowl = mi*16 + hi*4 + r;
        int rowg = base + rowl;
        int c = sC[rowl];
        float shv = bf2f(sA[sidx(rowl, col)]);
        float z  = sigm(g_tz[c*256+col] + accz[mi][ni][r]);
        float ph = tanh_f(g_th[c*256+col] + acch[mi][ni][r]);
        float hn = (1.0f - z)*shv + z*ph;
        if (rowg == 0) hn = 0.f;
        sB[sidx(rowl,col)] = f2bf(hn);
      }
    }
  __syncthreads();   // sB = h_new visible; sA free

  u8* sUb = (u8*)sA;  // fp8 uh staging, 256B/row (reuses sA)

  if (!last){
    // ---- Uh GEMM: h_new x Ur^T -> fp8 bytes into sUb ----
    f32x4 accu[2][4];
    #pragma unroll
    for (int i=0;i<2;i++)
      #pragma unroll
      for (int j=0;j<4;j++) accu[i][j]=(f32x4){0,0,0,0};
    for (int kt = 0; kt < 8; kt++){
      int k0 = kt*32;
      bf16x8 aF[2], bF[4];
      aF[0] = ldsA(sB, 0, lane, k0);
      aF[1] = ldsA(sB, 16, lane, k0);
      #pragma unroll
      for (int i=0;i<4;i++) bF[i] = ldgB(Ur, 256, 0, n0w + i*16, lane, k0);
      #pragma unroll
      for (int mi=0;mi<2;mi++)
        #pragma unroll
        for (int ni=0;ni<4;ni++) accu[mi][ni] = mfma16(aF[mi], bF[ni], accu[mi][ni]);
    }
    #pragma unroll
    for (int mi=0;mi<2;mi++)
      #pragma unroll
      for (int ni=0;ni<4;ni++){
        int col = n0w + ni*16 + ln;
        #pragma unroll
        for (int r=0;r<4;r++){
          int rowl = mi*16 + hi*4 + r;
          float v = accu[mi][ni][r];
          int pk = __builtin_amdgcn_cvt_pk_fp8_f32(v, v, 0, 0);
          sUb[rowl*256 + col] = (u8)(pk & 0xFF);
        }
      }
    __syncthreads();

    // ---- SCATTER: each wave pushes its 8 rows to all reader slots ----
    for (int i = 0; i < 8; i++){
      int rowl = w*8 + i;
      int j = base + rowl;
      int off = g_boff[j], deg = g_bcnt[j];
      for (int d = 0; d < deg; d++){
        size_t slot = (size_t)g_bsl[off + d];
        u8* dp = dst + slot*HU_B;
        if (lane < 32)
          *(u32x4*)(dp + (size_t)lane*16) = *(const u32x4*)(sB + sidx(rowl, lane*8));
        else if (lane < 48)
          *(u32x4*)(dp + 512 + (size_t)(lane-32)*16) = *(const u32x4*)(sUb + rowl*256 + (lane-32)*16);
      }
    }
  } else {
    // ---- last: scatter h-only to tail-expanded buffer via agraph CSR ----
    for (int i = 0; i < 8; i++){
      int rowl = w*8 + i;
      int j = base + rowl;
      int off = g_aoff[j], deg = g_acnt[j];
      for (int d = 0; d < deg; d++){
        size_t slot = (size_t)g_asl[off + d];
        if (lane < 32)
          *(u32x4*)(g_texp + slot*512 + (size_t)lane*16) = *(const u32x4*)(sB + sidx(rowl, lane*8));
      }
    }
  }
}

// ---------------- K5: tail (streaming texp + O1 relu + O2) ------------------
__global__ __launch_bounds__(256) void k_tail(const int* fnode, void* out_v){
  __shared__ __align__(16) ushort_t sT[64*256];
  const ushort_t* O1  = c_w + OFF_O1;
  const ushort_t* O2  = c_w + OFF_O2;
  const ushort_t* O2b = c_w + OFF_O2b;
  int base = blockIdx.x*64, t = threadIdx.x;
  int w = t>>6, lane = t&63;
  int sub = lane & 31, half = lane >> 5;

  auto tissue = [&](int p, bf16x8 (&hv)[KA]){
    int rowl = w*16 + 2*p + half;
    int a = base + rowl;
    int aa = (a < AA) ? a : 0;
    const u8* rp0 = g_texp + (size_t)aa*KA*512;
    #pragma unroll
    for (int k = 0; k < KA; k++)
      hv[k] = *(const bf16x8*)(rp0 + (size_t)k*512 + sub*16);
  };
  auto tproc = [&](int p, bf16x8 (&hv)[KA]){
    int rowl = w*16 + 2*p + half;
    float s[8] = {0,0,0,0,0,0,0,0};
    #pragma unroll
    for (int k = 0; k < KA; k++)
      #pragma unroll
      for (int e = 0; e < 8; e++) s[e] += bf2f((ushort_t)hv[k][e]);
    u16x8 pk;
    #pragma unroll
    for (int e = 0; e < 8; e++) pk[e] = f2bf(s[e]);
    *(u16x8*)(sT + sidx(rowl, sub*8)) = pk;
  };
  {
    bf16x8 b0[KA], b1[KA];
    tissue(0, b0); tissue(1, b1);
    SBAR();
    tproc(0, b0);  tissue(2, b0);
    SBAR();
    tproc(1, b1);  tissue(3, b1);
    SBAR();
    tproc(2, b0);  tissue(4, b0);
    SBAR();
    tproc(3, b1);  tissue(5, b1);
    SBAR();
    tproc(4, b0);  tissue(6, b0);
    SBAR();
    tproc(5, b1);  tissue(7, b1);
    SBAR();
    tproc(6, b0);
    tproc(7, b1);
  }
  __syncthreads();
  int n0w = w*64, ln = lane&15, hi = lane>>4;
  f32x4 acc[4][4];
  #pragma unroll
  for (int i=0;i<4;i++)
    #pragma unroll
    for (int j=0;j<4;j++) acc[i][j]=(f32x4){0,0,0,0};
  for (int kt = 0; kt < 8; kt++){
    int k0 = kt*32;
    bf16x8 aF[4], bF[4];
    #pragma unroll
    for (int i=0;i<4;i++) aF[i] = ldsA(sT, i*16, lane, k0);
    #pragma unroll
    for (int i=0;i<4;i++) bF[i] = ldgB(O1, 512, 256, n0w + i*16, lane, k0);
    #pragma unroll
    for (int mi=0;mi<4;mi++)
      #pragma unroll
      for (int ni=0;ni<4;ni++) acc[mi][ni] = mfma16(aF[mi], bF[ni], acc[mi][ni]);
  }
  __syncthreads();
  #pragma unroll
  for (int mi=0;mi<4;mi++)
    #pragma unroll
    for (int ni=0;ni<4;ni++){
      int col = n0w + ni*16 + ln;
      #pragma unroll
      for (int r=0;r<4;r++){
        int rowl = mi*16 + hi*4 + r;
        int a = base + rowl;
        int tt = (a < AA) ? fnode[a] : 0;
        float pre = g_to1[tt*256+col] + acc[mi][ni][r];
        sT[sidx(rowl,col)] = f2bf(fmaxf(pre, 0.f));
      }
    }
  __syncthreads();
  f32x4 acco[4][4];
  #pragma unroll
  for (int i=0;i<4;i++)
    #pragma unroll
    for (int j=0;j<4;j++) acco[i][j]=(f32x4){0,0,0,0};
  for (int kt = 0; kt < 8; kt++){
    int k0 = kt*32;
    bf16x8 aF[4], bF[4];
    #pragma unroll
    for (int i=0;i<4;i++) aF[i] = ldsA(sT, i*16, lane, k0);
    #pragma unroll
    for (int i=0;i<4;i++) bF[i] = ldgB(O2, 256, 0, n0w + i*16, lane, k0);
    #pragma unroll
    for (int mi=0;mi<4;mi++)
      #pragma unroll
      for (int ni=0;ni<4;ni++) acco[mi][ni] = mfma16(aF[mi], bF[ni], acco[mi][ni]);
  }
  int isf32 = g_isf32;
  #pragma unroll
  for (int mi=0;mi<4;mi++)
    #pragma unroll
    for (int ni=0;ni<4;ni++){
      int col = n0w + ni*16 + ln;
      float bias = bf2f(O2b[col]);
      #pragma unroll
      for (int r=0;r<4;r++){
        int rowg = base + mi*16 + hi*4 + r;
        if (rowg < AA){
          float v = acco[mi][ni][r] + bias;
          if (isf32) ((float*)out_v)[(size_t)rowg*256 + col] = v;
          else       ((ushort_t*)out_v)[(size_t)rowg*256 + col] = f2bf(v);
        }
      }
    }
}

// ---------------- launch ----------------------------------------------------
extern "C" void kernel_launch(void* const* d_in, const int* in_sizes, int n_in,
                              void* d_out, int out_size, void* d_ws, size_t ws_size,
                              hipStream_t stream) {
  const int* fnode = (const int*)d_in[13];
  const int* fsrc  = (const int*)d_in[14];
  const int* fbond = (const int*)d_in[15];
  const int* agraph = (const int*)d_in[16];
  const int* bgraph = (const int*)d_in[17];
  // depth is fixed at 4 by the problem setup

  k_detect<<<1, 256, 0, stream>>>((const ushort_t*)d_in[0]);
  k_convert<<<(W_TOTAL + 255)/256, 256, 0, stream>>>(
      d_in[0], d_in[1], d_in[2], d_in[3], d_in[4], d_in[5], d_in[6],
      d_in[7], d_in[8], d_in[9], d_in[10], d_in[11], d_in[12]);
  k_tables<<<3*NC + NATOM, 256, 0, stream>>>();
  k_cidx<<<(MM + 255)/256, 256, 0, stream>>>(fnode, fsrc, fbond);
  // inverse-CSR build (per call; deterministic output)
  k_zero<<<(MM + 255)/256, 256, 0, stream>>>();
  k_count<<<(NS_B + NS_A + 255)/256, 256, 0, stream>>>(bgraph, agraph);
  k_alloc<<<(MM + 255)/256, 256, 0, stream>>>();
  k_fill<<<(NS_B + NS_A + 255)/256, 256, 0, stream>>>(bgraph, agraph);
  k_tab0<<<481, 256, 0, stream>>>();                       // h1|uh1 combo table
  // GRU iters 2..4 (iter 1 is the table itself):
  k_fused<<<MM/32, 256, 0, stream>>>(bgraph, 1, 1, 0);     // it2: table -> exp0
  k_fused<<<MM/32, 256, 0, stream>>>(bgraph, 0, 0, 0);     // it3: exp0 -> exp1
  k_fused<<<MM/32, 256, 0, stream>>>(bgraph, 1, 0, 1);     // it4: exp1 -> texp (h only)
  k_tail<<<(AA + 63)/64, 256, 0, stream>>>(fnode, (void*)d_out);
}

// Round 15
// 1360.752 us; speedup vs baseline: 1.5586x; 1.5586x over previous
//
#include <hip/hip_runtime.h>

#define MM 200000      // messages
#define AA 100000      // atoms
#define KA 6
#define KB 5
#define NATOM 120
#define NBOND 4
#define NC (NATOM*NBOND)   // 480 combos
#define HH 256
#define HU_B 768           // bytes per state row: [h bf16 512B | uh fp8 256B]

typedef unsigned char  u8;
typedef unsigned short ushort_t;
typedef __attribute__((ext_vector_type(8))) short bf16x8;
typedef __attribute__((ext_vector_type(8))) unsigned short u16x8;
typedef __attribute__((ext_vector_type(4))) float f32x4;
typedef __attribute__((ext_vector_type(2))) float f32x2;
typedef __attribute__((ext_vector_type(4))) unsigned int u32x4;
typedef __attribute__((ext_vector_type(2))) unsigned int u32x2;

#define SBAR() __builtin_amdgcn_sched_barrier(0)

// canonical bf16 weight arena offsets (ushort elements)
#define OFF_Ea   0
#define OFF_Eb   30720
#define OFF_Wz   31744
#define OFF_Wzb  228352
#define OFF_Wr   228608
#define OFF_Ur   359680
#define OFF_Urb  425216
#define OFF_Wh   425472
#define OFF_Whb  622080
#define OFF_O1   622336
#define OFF_O1b  753408
#define OFF_O2   753664
#define OFF_O2b  819200
#define W_TOTAL  819456

// ---------------- static device state ----------------
__device__ u8       g_hu0[(size_t)MM*HU_B];  // ping
__device__ u8       g_hu1[(size_t)MM*HU_B];  // pong
__device__ u8       g_tab[481*HU_B];         // h1|uh1 per combo (row 480 = zeros)
__device__ ushort_t g_trb[NC*HH];     // bf16: x@Wr^T + Ur_b per combo
__device__ float    g_tz[NC*HH];      // x-part of z preact + Wz_b
__device__ float    g_th[NC*HH];      // x-part of h preact + Wh_b
__device__ float    g_to1[NATOM*HH];  // hnode-part of O1 preact + O1_b
__device__ int      g_cidx[MM];
__device__ ushort_t c_w[W_TOTAL];     // canonical bf16 weights
__device__ int      g_isf32;          // 1 if float inputs are f32

// ---------------- helpers ----------------
__device__ inline float bf2f(ushort_t u){ return __uint_as_float(((unsigned)u)<<16); }
__device__ inline ushort_t f2bf(float f){
  unsigned u = __float_as_uint(f);
  unsigned r = (u + 0x7FFFu + ((u>>16)&1u)) >> 16;
  return (ushort_t)r;
}
// fast sigmoid/tanh via v_rcp_f32 (~1ulp)
__device__ inline float sigm(float x){
  return __builtin_amdgcn_rcpf(1.0f + __expf(-x));
}
__device__ inline float tanh_f(float x){
  float ax = fabsf(x);
  float e = __expf(-2.0f*ax);
  float t = (1.0f - e) * __builtin_amdgcn_rcpf(1.0f + e);
  return copysignf(t, x);
}
// LDS swizzle: ushort-index within a [rows][256] bf16 tile (XOR bits 3..5 by row&7)
__device__ inline int sidx(int row, int col){ return row*256 + (col ^ ((row&7)<<3)); }

__device__ inline bf16x8 ldsA(const ushort_t* tile, int m0, int lane, int k0){
  int row = m0 + (lane & 15);
  int col = k0 + 8*(lane>>4);
  return *(const bf16x8*)(tile + sidx(row, col));
}
__device__ inline bf16x8 ldgB(const ushort_t* W, int ldw, int koff, int n0, int lane, int k0){
  int n = n0 + (lane & 15);
  int k = koff + k0 + 8*(lane>>4);
  return *(const bf16x8*)(W + n*ldw + k);
}
__device__ inline f32x4 mfma16(bf16x8 a, bf16x8 b, f32x4 c){
  return __builtin_amdgcn_mfma_f32_16x16x32_bf16(a, b, c, 0, 0, 0);
}
__device__ inline void st16(u8* p, const ushort_t* lds_src){
  *(u32x4*)p = *(const u32x4*)lds_src;
}
// encode 8 bf16 (from LDS) -> 8 fp8 bytes
__device__ inline u32x2 enc_fp8x8(const ushort_t* s){
  u32x2 o;
  int w0 = __builtin_amdgcn_cvt_pk_fp8_f32(bf2f(s[0]), bf2f(s[1]), 0, 0);
  w0     = __builtin_amdgcn_cvt_pk_fp8_f32(bf2f(s[2]), bf2f(s[3]), w0, 1);
  int w1 = __builtin_amdgcn_cvt_pk_fp8_f32(bf2f(s[4]), bf2f(s[5]), 0, 0);
  w1     = __builtin_amdgcn_cvt_pk_fp8_f32(bf2f(s[6]), bf2f(s[7]), w1, 1);
  o.x = (unsigned)w0; o.y = (unsigned)w1;
  return o;
}

// ---------------- K-detect: is the float data f32 or bf16? ------------------
__global__ __launch_bounds__(256) void k_detect(const ushort_t* Ea_raw){
  __shared__ int sbad;
  if (threadIdx.x == 0) sbad = 0;
  __syncthreads();
  float v = bf2f(Ea_raw[2*threadIdx.x]);
  float av = fabsf(v);
  int bad = (av > 1e4f) || (av != 0.0f && av < 1e-30f);
  atomicAdd(&sbad, bad);
  __syncthreads();
  if (threadIdx.x == 0) g_isf32 = (sbad > 64) ? 1 : 0;
}

// ---------------- K-convert: build canonical bf16 arena ---------------------
__global__ __launch_bounds__(256) void k_convert(
    const void* Ea, const void* Eb, const void* Wz, const void* Wzb,
    const void* Wr, const void* Ur, const void* Urb, const void* Wh,
    const void* Whb, const void* O1, const void* O1b, const void* O2,
    const void* O2b)
{
  int idx = blockIdx.x*256 + threadIdx.x;
  if (idx >= W_TOTAL) return;
  const void* src; int j;
  if      (idx < OFF_Eb)  { src = Ea;  j = idx - OFF_Ea; }
  else if (idx < OFF_Wz)  { src = Eb;  j = idx - OFF_Eb; }
  else if (idx < OFF_Wzb) { src = Wz;  j = idx - OFF_Wz; }
  else if (idx < OFF_Wr)  { src = Wzb; j = idx - OFF_Wzb; }
  else if (idx < OFF_Ur)  { src = Wr;  j = idx - OFF_Wr; }
  else if (idx < OFF_Urb) { src = Ur;  j = idx - OFF_Ur; }
  else if (idx < OFF_Wh)  { src = Urb; j = idx - OFF_Urb; }
  else if (idx < OFF_Whb) { src = Wh;  j = idx - OFF_Wh; }
  else if (idx < OFF_O1)  { src = Whb; j = idx - OFF_Whb; }
  else if (idx < OFF_O1b) { src = O1;  j = idx - OFF_O1; }
  else if (idx < OFF_O2)  { src = O1b; j = idx - OFF_O1b; }
  else if (idx < OFF_O2b) { src = O2;  j = idx - OFF_O2; }
  else                    { src = O2b; j = idx - OFF_O2b; }
  ushort_t v;
  if (g_isf32) v = f2bf(((const float*)src)[j]);
  else         v = ((const ushort_t*)src)[j];
  c_w[idx] = v;
}

// ---------------- K0: build tables -----------------------------------------
__global__ __launch_bounds__(256) void k_tables()
{
  const ushort_t* Ea  = c_w + OFF_Ea;
  const ushort_t* Eb  = c_w + OFF_Eb;
  int b = blockIdx.x, o = threadIdx.x;
  if (b < 3*NC) {
    int t = b / NC, c = b % NC, a = c >> 2, bd = c & 3;
    const ushort_t* W; const ushort_t* bias; int ldw;
    if (t == 0)      { W = c_w + OFF_Wr; bias = c_w + OFF_Urb; ldw = 512; }
    else if (t == 1) { W = c_w + OFF_Wz; bias = c_w + OFF_Wzb; ldw = 768; }
    else             { W = c_w + OFF_Wh; bias = c_w + OFF_Whb; ldw = 768; }
    float acc = bf2f(bias[o]);
    const ushort_t* wrow = W + o*ldw;
    for (int d = 0; d < 256; d++) acc += bf2f(Ea[a*256+d]) * bf2f(wrow[d]);
    for (int d = 0; d < 256; d++) acc += bf2f(Eb[bd*256+d]) * bf2f(wrow[256+d]);
    if (t == 0)      g_trb[c*256 + o] = f2bf(acc);
    else if (t == 1) g_tz[c*256 + o] = acc;
    else             g_th[c*256 + o] = acc;
  } else {
    int a = b - 3*NC;
    float acc = bf2f(c_w[OFF_O1b + o]);
    const ushort_t* wrow = c_w + OFF_O1 + o*512;
    for (int d = 0; d < 256; d++) acc += bf2f(Ea[a*256+d]) * bf2f(wrow[d]);
    g_to1[a*256 + o] = acc;
  }
}

// ---------------- K1: combo index per message ------------------------------
__global__ __launch_bounds__(256) void k_cidx(const int* fnode, const int* fsrc, const int* fbond){
  int m = blockIdx.x*256 + threadIdx.x;
  if (m >= MM) return;
  g_cidx[m] = fnode[fsrc[m]]*4 + fbond[m];
}

// ---------------- K-tab0: 481-row h1|uh1 combo table ------------------------
__global__ __launch_bounds__(256) void k_tab0(){
  __shared__ ushort_t sh[256];
  int b = blockIdx.x, o = threadIdx.x;
  u8* row = g_tab + (size_t)b*HU_B;
  if (b == 480){
    ((ushort_t*)row)[o] = 0;
    row[512 + o] = 0;   // fp8 zero
    return;
  }
  float h = sigm(g_tz[b*256+o]) * tanh_f(g_th[b*256+o]);
  ushort_t hb = f2bf(h);
  ((ushort_t*)row)[o] = hb;
  sh[o] = hb;
  __syncthreads();
  const ushort_t* ur = c_w + OFF_Ur + o*256;
  float acc = 0.f;
  for (int d = 0; d < 256; d++) acc += bf2f(sh[d]) * bf2f(ur[d]);
  int pk = __builtin_amdgcn_cvt_pk_fp8_f32(acc, acc, 0, 0);
  row[512 + o] = (u8)(pk & 0xFF);
}

// ---------------- K-fused: gather + GRU update + Uh GEMM (ping-pong) -------
// 32-row tiles; h bf16 (16B loads) + uh fp8 (8B loads) -> 6 lines/neighbor row
__global__ __launch_bounds__(256,4) void k_fused(const int* __restrict__ bgraph, int rd, int tbl, int last){
  __shared__ __align__(16) ushort_t sA[32*256];  // sum_h -> uh_new staging
  __shared__ __align__(16) ushort_t sB[32*256];  // sum_gated -> h_new
  __shared__ int sC[32];
  __shared__ int sJ[32*KB];
  const u8* __restrict__ hup = tbl ? g_tab : (rd ? g_hu1 : g_hu0);
  u8* hun = rd ? g_hu0 : g_hu1;
  const ushort_t* Wz = c_w + OFF_Wz;
  const ushort_t* Wh = c_w + OFF_Wh;
  const ushort_t* Ur = c_w + OFF_Ur;
  int base = blockIdx.x*32, t = threadIdx.x;
  int w = t>>6, lane = t&63;
  int sub = lane & 31, half = lane >> 5;

  // ---- header: combo indices + (translated) bgraph slice into LDS ----
  if (t < 32)  sC[t] = g_cidx[base + t];
  if (t < 32*KB){
    int j = bgraph[base*KB + t];
    sJ[t] = tbl ? ((j == 0) ? 480 : g_cidx[j]) : j;
  }
  __syncthreads();

  // ---- pipelined gather: 8 rows/wave as 4 pairs; lane covers 8 cols ----
  auto issue = [&](int p, bf16x8 (&hv)[KB], u32x2 (&uv)[KB], bf16x8& trv){
    int row = w*8 + 2*p + half;
    trv = *(const bf16x8*)(g_trb + sC[row]*256 + sub*8);
    #pragma unroll
    for (int k = 0; k < KB; k++){
      const u8* rp = hup + (size_t)sJ[row*KB + k]*HU_B;
      hv[k] = *(const bf16x8*)(rp + sub*16);
      uv[k] = *(const u32x2*)(rp + 512 + sub*8);
    }
  };
  auto process = [&](int p, bf16x8 (&hv)[KB], u32x2 (&uv)[KB], bf16x8& trv){
    int row = w*8 + 2*p + half;
    float tre[8];
    #pragma unroll
    for (int e = 0; e < 8; e++) tre[e] = bf2f((ushort_t)trv[e]);
    float sh[8] = {0,0,0,0,0,0,0,0};
    float sg[8] = {0,0,0,0,0,0,0,0};
    #pragma unroll
    for (int k = 0; k < KB; k++){
      f32x2 d0 = __builtin_amdgcn_cvt_pk_f32_fp8(uv[k].x, 0);
      f32x2 d1 = __builtin_amdgcn_cvt_pk_f32_fp8(uv[k].x, 1);
      f32x2 d2 = __builtin_amdgcn_cvt_pk_f32_fp8(uv[k].y, 0);
      f32x2 d3 = __builtin_amdgcn_cvt_pk_f32_fp8(uv[k].y, 1);
      float uvf[8] = {d0.x, d0.y, d1.x, d1.y, d2.x, d2.y, d3.x, d3.y};
      #pragma unroll
      for (int e = 0; e < 8; e++){
        float h = bf2f((ushort_t)hv[k][e]);
        float r = sigm(tre[e] + uvf[e]);
        sh[e] += h;
        sg[e] += r*h;
      }
    }
    u16x8 ph, pg;
    #pragma unroll
    for (int e = 0; e < 8; e++){ ph[e] = f2bf(sh[e]); pg[e] = f2bf(sg[e]); }
    *(u16x8*)(sA + sidx(row, sub*8)) = ph;
    *(u16x8*)(sB + sidx(row, sub*8)) = pg;
  };
  {
    bf16x8 h0[KB], h1[KB];
    u32x2 u0[KB], u1[KB];
    bf16x8 t0v, t1v;
    issue(0, h0, u0, t0v);
    issue(1, h1, u1, t1v);
    SBAR();
    process(0, h0, u0, t0v);
    issue(2, h0, u0, t0v);
    SBAR();
    process(1, h1, u1, t1v);
    issue(3, h1, u1, t1v);
    SBAR();
    process(2, h0, u0, t0v);
    process(3, h1, u1, t1v);
  }
  __syncthreads();

  // ---- GEMM phase: z (sA x Wz) and pre_h (sB x Wh), M=32 ----
  int n0w = w*64, ln = lane&15, hi = lane>>4;
  f32x4 accz[2][4], acch[2][4];
  #pragma unroll
  for (int i=0;i<2;i++)
    #pragma unroll
    for (int j=0;j<4;j++){ accz[i][j]=(f32x4){0,0,0,0}; acch[i][j]=(f32x4){0,0,0,0}; }
  for (int kt = 0; kt < 8; kt++){
    int k0 = kt*32;
    bf16x8 aF[2], bF[4];
    aF[0] = ldsA(sA, 0, lane, k0);
    aF[1] = ldsA(sA, 16, lane, k0);
    #pragma unroll
    for (int i=0;i<4;i++) bF[i] = ldgB(Wz, 768, 512, n0w + i*16, lane, k0);
    #pragma unroll
    for (int mi=0;mi<2;mi++)
      #pragma unroll
      for (int ni=0;ni<4;ni++) accz[mi][ni] = mfma16(aF[mi], bF[ni], accz[mi][ni]);
  }
  for (int kt = 0; kt < 8; kt++){
    int k0 = kt*32;
    bf16x8 aF[2], bF[4];
    aF[0] = ldsA(sB, 0, lane, k0);
    aF[1] = ldsA(sB, 16, lane, k0);
    #pragma unroll
    for (int i=0;i<4;i++) bF[i] = ldgB(Wh, 768, 512, n0w + i*16, lane, k0);
    #pragma unroll
    for (int mi=0;mi<2;mi++)
      #pragma unroll
      for (int ni=0;ni<4;ni++) acch[mi][ni] = mfma16(aF[mi], bF[ni], acch[mi][ni]);
  }
  __syncthreads();   // all waves done reading sA/sB

  // ---- epilogue: GRU update into sB (LDS only) ----
  #pragma unroll
  for (int mi=0;mi<2;mi++)
    #pragma unroll
    for (int ni=0;ni<4;ni++){
      int col = n0w + ni*16 + ln;
      #pragma unroll
      for (int r=0;r<4;r++){
        int rowl = mi*16 + hi*4 + r;
        int rowg = base + rowl;
        int c = sC[rowl];
        float shv = bf2f(sA[sidx(rowl, col)]);
        float z  = sigm(g_tz[c*256+col] + accz[mi][ni][r]);
        float ph = tanh_f(g_th[c*256+col] + acch[mi][ni][r]);
        float hn = (1.0f - z)*shv + z*ph;
        if (rowg == 0) hn = 0.f;
        sB[sidx(rowl,col)] = f2bf(hn);
      }
    }
  __syncthreads();   // sB = h_new visible; sA free

  if (!last){
    // ---- Uh GEMM: h_new x Ur^T, stage into sA (bf16; fp8-encoded at write) ----
    f32x4 accu[2][4];
    #pragma unroll
    for (int i=0;i<2;i++)
      #pragma unroll
      for (int j=0;j<4;j++) accu[i][j]=(f32x4){0,0,0,0};
    for (int kt = 0; kt < 8; kt++){
      int k0 = kt*32;
      bf16x8 aF[2], bF[4];
      aF[0] = ldsA(sB, 0, lane, k0);
      aF[1] = ldsA(sB, 16, lane, k0);
      #pragma unroll
      for (int i=0;i<4;i++) bF[i] = ldgB(Ur, 256, 0, n0w + i*16, lane, k0);
      #pragma unroll
      for (int mi=0;mi<2;mi++)
        #pragma unroll
        for (int ni=0;ni<4;ni++) accu[mi][ni] = mfma16(aF[mi], bF[ni], accu[mi][ni]);
    }
    #pragma unroll
    for (int mi=0;mi<2;mi++)
      #pragma unroll
      for (int ni=0;ni<4;ni++){
        int col = n0w + ni*16 + ln;
        #pragma unroll
        for (int r=0;r<4;r++){
          int rowl = mi*16 + hi*4 + r;
          sA[sidx(rowl, col)] = f2bf(accu[mi][ni][r]);
        }
      }
    __syncthreads();
  }

  // ---- coalesced write phase: h bf16 (sB) always; uh fp8 (sA) if !last ----
  {
    #pragma unroll
    for (int it = 0; it < 4; it++){
      int flat = it*2048 + t*8;
      int row = flat >> 8, col = flat & 255;
      u8* rb = hun + (size_t)(base+row)*HU_B;
      st16(rb + col*2, sB + sidx(row, col));
      if (!last){
        u32x2 enc = enc_fp8x8(sA + sidx(row, col));
        *(u32x2*)(rb + 512 + col) = enc;
      }
    }
  }
}

// ---------------- K5: tail (agraph gather + O1 relu + O2) ------------------
__global__ __launch_bounds__(256) void k_tail(const int* agraph, const int* fnode,
                                              void* out_v, int rd){
  __shared__ __align__(16) ushort_t sT[64*256];
  const u8* __restrict__ hup = rd ? g_hu1 : g_hu0;
  const ushort_t* O1  = c_w + OFF_O1;
  const ushort_t* O2  = c_w + OFF_O2;
  const ushort_t* O2b = c_w + OFF_O2b;
  int base = blockIdx.x*64, t = threadIdx.x;
  int w = t>>6, lane = t&63;
  int sub = lane & 31, half = lane >> 5;

  auto tissue = [&](int p, bf16x8 (&hv)[KA]){
    int rowl = w*16 + 2*p + half;
    int a = base + rowl;
    int aa = (a < AA) ? a : 0;
    #pragma unroll
    for (int k = 0; k < KA; k++){
      int j = agraph[aa*KA + k];
      hv[k] = *(const bf16x8*)(hup + (size_t)j*HU_B + sub*16);
    }
  };
  auto tproc = [&](int p, bf16x8 (&hv)[KA]){
    int rowl = w*16 + 2*p + half;
    float s[8] = {0,0,0,0,0,0,0,0};
    #pragma unroll
    for (int k = 0; k < KA; k++)
      #pragma unroll
      for (int e = 0; e < 8; e++) s[e] += bf2f((ushort_t)hv[k][e]);
    u16x8 pk;
    #pragma unroll
    for (int e = 0; e < 8; e++) pk[e] = f2bf(s[e]);
    *(u16x8*)(sT + sidx(rowl, sub*8)) = pk;
  };
  {
    bf16x8 b0[KA], b1[KA];
    tissue(0, b0); tissue(1, b1);
    SBAR();
    tproc(0, b0);  tissue(2, b0);
    SBAR();
    tproc(1, b1);  tissue(3, b1);
    SBAR();
    tproc(2, b0);  tissue(4, b0);
    SBAR();
    tproc(3, b1);  tissue(5, b1);
    SBAR();
    tproc(4, b0);  tissue(6, b0);
    SBAR();
    tproc(5, b1);  tissue(7, b1);
    SBAR();
    tproc(6, b0);
    tproc(7, b1);
  }
  __syncthreads();
  int n0w = w*64, ln = lane&15, hi = lane>>4;
  f32x4 acc[4][4];
  #pragma unroll
  for (int i=0;i<4;i++)
    #pragma unroll
    for (int j=0;j<4;j++) acc[i][j]=(f32x4){0,0,0,0};
  for (int kt = 0; kt < 8; kt++){
    int k0 = kt*32;
    bf16x8 aF[4], bF[4];
    #pragma unroll
    for (int i=0;i<4;i++) aF[i] = ldsA(sT, i*16, lane, k0);
    #pragma unroll
    for (int i=0;i<4;i++) bF[i] = ldgB(O1, 512, 256, n0w + i*16, lane, k0);
    #pragma unroll
    for (int mi=0;mi<4;mi++)
      #pragma unroll
      for (int ni=0;ni<4;ni++) acc[mi][ni] = mfma16(aF[mi], bF[ni], acc[mi][ni]);
  }
  __syncthreads();
  #pragma unroll
  for (int mi=0;mi<4;mi++)
    #pragma unroll
    for (int ni=0;ni<4;ni++){
      int col = n0w + ni*16 + ln;
      #pragma unroll
      for (int r=0;r<4;r++){
        int rowl = mi*16 + hi*4 + r;
        int a = base + rowl;
        int tt = (a < AA) ? fnode[a] : 0;
        float pre = g_to1[tt*256+col] + acc[mi][ni][r];
        sT[sidx(rowl,col)] = f2bf(fmaxf(pre, 0.f));
      }
    }
  __syncthreads();
  f32x4 acco[4][4];
  #pragma unroll
  for (int i=0;i<4;i++)
    #pragma unroll
    for (int j=0;j<4;j++) acco[i][j]=(f32x4){0,0,0,0};
  for (int kt = 0; kt < 8; kt++){
    int k0 = kt*32;
    bf16x8 aF[4], bF[4];
    #pragma unroll
    for (int i=0;i<4;i++) aF[i] = ldsA(sT, i*16, lane, k0);
    #pragma unroll
    for (int i=0;i<4;i++) bF[i] = ldgB(O2, 256, 0, n0w + i*16, lane, k0);
    #pragma unroll
    for (int mi=0;mi<4;mi++)
      #pragma unroll
      for (int ni=0;ni<4;ni++) acco[mi][ni] = mfma16(aF[mi], bF[ni], acco[mi][ni]);
  }
  int isf32 = g_isf32;
  #pragma unroll
  for (int mi=0;mi<4;mi++)
    #pragma unroll
    for (int ni=0;ni<4;ni++){
      int col = n0w + ni*16 + ln;
      float bias = bf2f(O2b[col]);
      #pragma unroll
      for (int r=0;r<4;r++){
        int rowg = base + mi*16 + hi*4 + r;
        if (rowg < AA){
          float v = acco[mi][ni][r] + bias;
          if (isf32) ((float*)out_v)[(size_t)rowg*256 + col] = v;
          else       ((ushort_t*)out_v)[(size_t)rowg*256 + col] = f2bf(v);
        }
      }
    }
}

// ---------------- launch ----------------------------------------------------
extern "C" void kernel_launch(void* const* d_in, const int* in_sizes, int n_in,
                              void* d_out, int out_size, void* d_ws, size_t ws_size,
                              hipStream_t stream) {
  const int* fnode = (const int*)d_in[13];
  const int* fsrc  = (const int*)d_in[14];
  const int* fbond = (const int*)d_in[15];
  const int* agraph = (const int*)d_in[16];
  const int* bgraph = (const int*)d_in[17];
  // depth is fixed at 4 by the problem setup

  k_detect<<<1, 256, 0, stream>>>((const ushort_t*)d_in[0]);
  k_convert<<<(W_TOTAL + 255)/256, 256, 0, stream>>>(
      d_in[0], d_in[1], d_in[2], d_in[3], d_in[4], d_in[5], d_in[6],
      d_in[7], d_in[8], d_in[9], d_in[10], d_in[11], d_in[12]);
  k_tables<<<3*NC + NATOM, 256, 0, stream>>>();
  k_cidx<<<(MM + 255)/256, 256, 0, stream>>>(fnode, fsrc, fbond);
  k_tab0<<<481, 256, 0, stream>>>();                       // h1|uh1 combo table
  // GRU iters 2..4 (iter 1 is the table itself):
  k_fused<<<MM/32, 256, 0, stream>>>(bgraph, 1, 1, 0);     // it2: table -> g_hu0
  k_fused<<<MM/32, 256, 0, stream>>>(bgraph, 0, 0, 0);     // it3: g_hu0 -> g_hu1
  k_fused<<<MM/32, 256, 0, stream>>>(bgraph, 1, 0, 1);     // it4: g_hu1 -> g_hu0 (h only)
  k_tail<<<(AA + 63)/64, 256, 0, stream>>>(agraph, fnode, (void*)d_out, 0);
}